// Round 1
// baseline (214.653 us; speedup 1.0000x reference)
//
#include <hip/hip_runtime.h>

#define R_DIM 2048
#define C_DIM 16
#define O_DIM 32
#define I_DIM 16
#define B_DIM 64
#define B_CHUNK 32   // batch elements per block
#define NJ 8         // o-lanes per b in routing phase (each holds 4 o's)

// Block: 512 threads.
// Phase 1: thread=(c,o) computes u_hat[b] for 32 b's (W in regs, x via scalar loads).
// LDS: u_hat [32][512] fp32 (64 KB), XOR-swizzled for conflict-free transpose.
// Phase 2: thread=(b,j) j=0..7 holds u_hat[c][o=j+8k] (64 regs), full routing in
// registers; only cross-lane traffic is 3-step shfl_xor butterflies over 8 lanes.
__global__ __launch_bounds__(512, 4)
void capsule_routing_kernel(const float* __restrict__ x,
                            const float* __restrict__ W,
                            float* __restrict__ out) {
    __shared__ float u_lds[B_CHUNK * 512];

    const int tid = threadIdx.x;
    const int bid = blockIdx.x;
    const int r  = bid >> 1;
    const int b0 = (bid & 1) * B_CHUNK;

    // ---------------- Phase 1: u_hat = W[r,c,o,:] . x[b,r,:] ----------------
    {
        const int c = tid >> 5;      // 0..15
        const int o = tid & 31;      // 0..31

        // W[r,c,o,0:16] -> registers (coalesced: lane stride 64B, 4x float4)
        const float* wp = W + ((((size_t)r * C_DIM) + c) * O_DIM + o) * I_DIM;
        float w[16];
        #pragma unroll
        for (int q = 0; q < 4; ++q) {
            const float4 wv = *(const float4*)(wp + 4 * q);
            w[4*q + 0] = wv.x; w[4*q + 1] = wv.y; w[4*q + 2] = wv.z; w[4*q + 3] = wv.w;
        }

        float u[B_CHUNK];
        #pragma unroll
        for (int b = 0; b < B_CHUNK; ++b) {
            // uniform address (blockIdx/loop-derived) -> scalar loads
            const float* xp = x + (((size_t)(b0 + b) * R_DIM) + r) * I_DIM;
            float acc = 0.0f;
            #pragma unroll
            for (int q = 0; q < 4; ++q) {
                const float4 a = *(const float4*)(xp + 4 * q);
                acc = fmaf(w[4*q + 0], a.x, acc);
                acc = fmaf(w[4*q + 1], a.y, acc);
                acc = fmaf(w[4*q + 2], a.z, acc);
                acc = fmaf(w[4*q + 3], a.w, acc);
            }
            u[b] = acc;
        }

        // store swizzled: addr = b*512 + (idx ^ ((b&3)<<3)), idx = c*32+o = tid
        #pragma unroll
        for (int b = 0; b < B_CHUNK; ++b)
            u_lds[b * 512 + (tid ^ ((b & 3) << 3))] = u[b];
    }
    __syncthreads();

    // ---------------- Phase 2: dynamic routing (3 iterations) ----------------
    if (tid < B_CHUNK * NJ) {           // 256 active lanes, whole waves
        const int b   = tid >> 3;       // 0..31 (local)
        const int j   = tid & 7;        // 0..7
        const int swz = (b & 3) << 3;

        // u2[c*4+k] = u_hat[b][c][o = j + 8k]
        float u2[64];
        #pragma unroll
        for (int c = 0; c < 16; ++c) {
            #pragma unroll
            for (int k = 0; k < 4; ++k)
                u2[c * 4 + k] = u_lds[b * 512 + ((c * 32 + j + 8 * k) ^ swz)];
        }

        float bv[16];
        #pragma unroll
        for (int c = 0; c < 16; ++c) bv[c] = 0.0f;

        float s[4], g = 0.0f;

        #pragma unroll
        for (int it = 0; it < 3; ++it) {
            if (it == 0) {
                // softmax(0) = 1/16 uniform
                #pragma unroll
                for (int k = 0; k < 4; ++k) s[k] = 0.0f;
                #pragma unroll
                for (int c = 0; c < 16; ++c) {
                    #pragma unroll
                    for (int k = 0; k < 4; ++k) s[k] += u2[c * 4 + k];
                }
                #pragma unroll
                for (int k = 0; k < 4; ++k) s[k] *= 0.0625f;
            } else {
                float m = bv[0];
                #pragma unroll
                for (int c = 1; c < 16; ++c) m = fmaxf(m, bv[c]);
                float Z = 0.0f;
                #pragma unroll
                for (int k = 0; k < 4; ++k) s[k] = 0.0f;
                #pragma unroll
                for (int c = 0; c < 16; ++c) {
                    const float e = expf(bv[c] - m);
                    Z += e;
                    #pragma unroll
                    for (int k = 0; k < 4; ++k) s[k] = fmaf(e, u2[c * 4 + k], s[k]);
                }
                const float rZ = 1.0f / Z;
                #pragma unroll
                for (int k = 0; k < 4; ++k) s[k] *= rZ;
            }

            // squash scale: g = ||s|| / (1 + ||s||^2); v = g*s
            float nn = s[0]*s[0] + s[1]*s[1] + s[2]*s[2] + s[3]*s[3];
            nn += __shfl_xor(nn, 1);
            nn += __shfl_xor(nn, 2);
            nn += __shfl_xor(nn, 4);
            g = sqrtf(nn) / (1.0f + nn);

            if (it < 2) {
                // bv[c] += sum_o u_hat[c][o]*v[o] = g * sum_o u_hat[c][o]*s[o]
                #pragma unroll
                for (int c = 0; c < 16; ++c) {
                    float t = u2[c*4+0]*s[0] + u2[c*4+1]*s[1]
                            + u2[c*4+2]*s[2] + u2[c*4+3]*s[3];
                    t += __shfl_xor(t, 1);
                    t += __shfl_xor(t, 2);
                    t += __shfl_xor(t, 4);
                    bv[c] = fmaf(g, t, bv[c]);
                }
            }
        }

        // v[o] = g * s[k], o = j + 8k ; out[b_glob, r, o]
        float* op = out + (((size_t)(b0 + b) * R_DIM) + r) * O_DIM;
        #pragma unroll
        for (int k = 0; k < 4; ++k)
            op[j + 8 * k] = g * s[k];
    }
}

extern "C" void kernel_launch(void* const* d_in, const int* in_sizes, int n_in,
                              void* d_out, int out_size, void* d_ws, size_t ws_size,
                              hipStream_t stream) {
    const float* x   = (const float*)d_in[0];   // [64, 2048, 16]
    const float* W   = (const float*)d_in[1];   // [2048, 16, 32, 16]
    float*       out = (float*)d_out;           // [64, 2048, 32]

    dim3 grid(R_DIM * (B_DIM / B_CHUNK));       // 4096 blocks
    dim3 block(512);
    hipLaunchKernelGGL(capsule_routing_kernel, grid, block, 0, stream, x, W, out);
}

// Round 3
// 162.115 us; speedup vs baseline: 1.3241x; 1.3241x over previous
//
#include <hip/hip_runtime.h>

#define R_DIM 2048
#define C_DIM 16
#define O_DIM 32
#define I_DIM 16
#define B_DIM 64
#define BB 16   // batch rows per block

typedef short short8 __attribute__((ext_vector_type(8)));
typedef float f32x4  __attribute__((ext_vector_type(4)));

// truncate fp32 mantissa to bf16 (error-free residual arithmetic)
__device__ __forceinline__ float tbf(float v) {
    return __uint_as_float(__float_as_uint(v) & 0xffff0000u);
}
__device__ __forceinline__ short hi16(float h) {
    return (short)(__float_as_uint(h) >> 16);
}

struct Split3 { short8 h1, h2, h3; };

// error-free 3-way bf16 split of 8 consecutive fp32 (x = h1+h2+h3 to ~2^-24)
__device__ __forceinline__ Split3 split8(const float* p) {
    float f[8];
    *(float4*)(f)     = *(const float4*)(p);
    *(float4*)(f + 4) = *(const float4*)(p + 4);
    Split3 r;
    #pragma unroll
    for (int j = 0; j < 8; ++j) {
        const float a  = tbf(f[j]);
        const float d1 = f[j] - a;
        const float b  = tbf(d1);
        const float d2 = d1 - b;
        const float c  = tbf(d2);
        r.h1[j] = hi16(a); r.h2[j] = hi16(b); r.h3[j] = hi16(c);
    }
    return r;
}

// DPP 16-lane (row) all-reduce sum — pure VALU pipe, no DS traffic.
template<int CTRL>
__device__ __forceinline__ float dpp_add(float v) {
    int t = __builtin_amdgcn_update_dpp(0, __float_as_int(v), CTRL, 0xf, 0xf, true);
    return v + __int_as_float(t);
}
__device__ __forceinline__ float row16_sum(float v) {
    v = dpp_add<0xB1>(v);   // quad_perm xor1
    v = dpp_add<0x4E>(v);   // quad_perm xor2
    v = dpp_add<0x124>(v);  // row_ror:4
    v = dpp_add<0x128>(v);  // row_ror:8
    return v;
}

// XOR bank swizzle: conflict-free for both MFMA C-scatter (varies with q=b>>2)
// and routing reads (varies with b&3 within a wave's 4 b-rows).
__device__ __forceinline__ int sw(int b) { return ((b ^ (b >> 2)) & 3) << 3; }

// Block: 256 threads = 4 waves; one (r, 16-batch slice).
// Phase 1: u_hat[16b x 512n] = x . W^T via 6-term split-bf16 MFMA chain
//   (terms x_a*w_b with a+b<=4) -> fp32-grade u_hat on the matrix pipe.
// Phase 2: thread=(b=tid>>4, j=tid&15) owns o={2j,2j+1}; routing fully in
//   registers, reductions via DPP row16_sum.
__global__ __launch_bounds__(256, 4)
void capsule_routing_kernel(const float* __restrict__ x,
                            const float* __restrict__ W,
                            float* __restrict__ out) {
    __shared__ float u_lds[BB * 512];   // 32 KB

    const int tid = threadIdx.x;
    const int bid = blockIdx.x;
    const int r   = bid >> 2;
    const int b0  = (bid & 3) * BB;

    // ---------------- Phase 1: split-bf16 MFMA u_hat ----------------
    {
        const int lane = tid & 63;
        const int w    = tid >> 6;     // wave 0..3 -> n-tiles w*8..w*8+7
        const int q    = lane >> 4;    // k-quad (2,3 = zero pad)
        const int np   = lane & 15;    // m (batch) for A / n-col for B

        const short8 z8 = {0,0,0,0,0,0,0,0};
        Split3 as; as.h1 = z8; as.h2 = z8; as.h3 = z8;
        if (q < 2)
            as = split8(x + ((size_t)(b0 + np) * R_DIM + r) * I_DIM + q * 8);

        const f32x4 zero4 = {0.f, 0.f, 0.f, 0.f};
        f32x4 acc[8];
        #pragma unroll
        for (int t = 0; t < 8; ++t) {
            const int ntile = w * 8 + t;
            Split3 bs; bs.h1 = z8; bs.h2 = z8; bs.h3 = z8;
            if (q < 2)
                bs = split8(W + ((size_t)r * 512 + ntile * 16 + np) * I_DIM + q * 8);

            // smallest terms first: (1,3),(3,1),(2,2) ~2^-16; (2,1),(1,2) ~2^-8; (1,1)
            f32x4 a = __builtin_amdgcn_mfma_f32_16x16x32_bf16(as.h1, bs.h3, zero4, 0, 0, 0);
            a = __builtin_amdgcn_mfma_f32_16x16x32_bf16(as.h3, bs.h1, a, 0, 0, 0);
            a = __builtin_amdgcn_mfma_f32_16x16x32_bf16(as.h2, bs.h2, a, 0, 0, 0);
            a = __builtin_amdgcn_mfma_f32_16x16x32_bf16(as.h2, bs.h1, a, 0, 0, 0);
            a = __builtin_amdgcn_mfma_f32_16x16x32_bf16(as.h1, bs.h2, a, 0, 0, 0);
            a = __builtin_amdgcn_mfma_f32_16x16x32_bf16(as.h1, bs.h1, a, 0, 0, 0);
            acc[t] = a;
        }

        // C/D: col = lane&15 (=np, the n within tile), row = q*4+reg (=batch)
        #pragma unroll
        for (int t = 0; t < 8; ++t) {
            const int col = (w * 8 + t) * 16 + np;
            #pragma unroll
            for (int reg = 0; reg < 4; ++reg) {
                const int row = q * 4 + reg;
                u_lds[row * 512 + (col ^ sw(row))] = acc[t][reg];
            }
        }
    }
    __syncthreads();

    // ---------------- Phase 2: dynamic routing ----------------
    {
        const int b = tid >> 4;    // 0..15 local batch
        const int j = tid & 15;    // o-pair index
        const int s = sw(b);

        float u2[32];              // u_hat[b][c][o=2j,2j+1]
        #pragma unroll
        for (int c = 0; c < 16; ++c) {
            const float2 v2 = *(const float2*)&u_lds[b * 512 + ((c * 32 + 2 * j) ^ s)];
            u2[2 * c]     = v2.x;
            u2[2 * c + 1] = v2.y;
        }

        float bv[16];
        #pragma unroll
        for (int c = 0; c < 16; ++c) bv[c] = 0.0f;

        float s0 = 0.f, s1 = 0.f, g = 0.f;

        #pragma unroll
        for (int it = 0; it < 3; ++it) {
            if (it == 0) {
                s0 = 0.f; s1 = 0.f;
                #pragma unroll
                for (int c = 0; c < 16; ++c) { s0 += u2[2*c]; s1 += u2[2*c+1]; }
                s0 *= 0.0625f; s1 *= 0.0625f;
            } else {
                float m = bv[0];
                #pragma unroll
                for (int c = 1; c < 16; ++c) m = fmaxf(m, bv[c]);
                float Z = 0.f; s0 = 0.f; s1 = 0.f;
                #pragma unroll
                for (int c = 0; c < 16; ++c) {
                    const float e = __expf(bv[c] - m);
                    Z += e;
                    s0 = fmaf(e, u2[2*c],   s0);
                    s1 = fmaf(e, u2[2*c+1], s1);
                }
                const float rZ = __builtin_amdgcn_rcpf(Z);
                s0 *= rZ; s1 *= rZ;
            }

            // g = ||s|| / (1 + ||s||^2), norm over 32 o's (16 lanes x 2)
            const float nn = row16_sum(s0 * s0 + s1 * s1);
            g = sqrtf(nn) * __builtin_amdgcn_rcpf(1.0f + nn);

            if (it < 2) {
                #pragma unroll
                for (int c = 0; c < 16; ++c) {
                    const float t = row16_sum(fmaf(u2[2*c], s0, u2[2*c+1] * s1));
                    bv[c] = fmaf(g, t, bv[c]);
                }
            }
        }

        const float2 o2 = make_float2(g * s0, g * s1);
        *(float2*)(out + ((size_t)(b0 + b) * R_DIM + r) * O_DIM + 2 * j) = o2;
    }
}

extern "C" void kernel_launch(void* const* d_in, const int* in_sizes, int n_in,
                              void* d_out, int out_size, void* d_ws, size_t ws_size,
                              hipStream_t stream) {
    const float* x   = (const float*)d_in[0];   // [64, 2048, 16]
    const float* W   = (const float*)d_in[1];   // [2048, 16, 32, 16]
    float*       out = (float*)d_out;           // [64, 2048, 32]

    dim3 grid(R_DIM * (B_DIM / BB));            // 8192 blocks
    dim3 block(256);
    hipLaunchKernelGGL(capsule_routing_kernel, grid, block, 0, stream, x, W, out);
}

// Round 4
// 155.248 us; speedup vs baseline: 1.3826x; 1.0442x over previous
//
#include <hip/hip_runtime.h>

#define R_DIM 2048
#define C_DIM 16
#define O_DIM 32
#define I_DIM 16
#define B_DIM 64
#define BB 16   // batch rows per block

typedef short short8 __attribute__((ext_vector_type(8)));
typedef float f32x4  __attribute__((ext_vector_type(4)));

// RNE round fp32 -> bf16 bits (returns the fp32 value of the rounded bf16 too)
__device__ __forceinline__ unsigned rne16(unsigned u) {
    return (u + 0x7FFFu + ((u >> 16) & 1u)) & 0xFFFF0000u;
}

struct Split2 { short8 h1, h2; };

// 2-way RNE bf16 split of 8 consecutive fp32: x ~= h1 + h2, residual ~2^-18
__device__ __forceinline__ Split2 split2x8(const float* p) {
    float f[8];
    *(float4*)(f)     = *(const float4*)(p);
    *(float4*)(f + 4) = *(const float4*)(p + 4);
    Split2 r;
    #pragma unroll
    for (int j = 0; j < 8; ++j) {
        const unsigned u  = __float_as_uint(f[j]);
        const unsigned a  = rne16(u);                      // bf16(x) RNE
        const float    d  = f[j] - __uint_as_float(a);     // exact residual
        const unsigned v  = __float_as_uint(d);
        r.h1[j] = (short)(a >> 16);
        r.h2[j] = (short)(rne16(v) >> 16);
    }
    return r;
}

// DPP 16-lane (row) all-reduce sum — pure VALU pipe, no DS traffic.
template<int CTRL>
__device__ __forceinline__ float dpp_add(float v) {
    int t = __builtin_amdgcn_update_dpp(0, __float_as_int(v), CTRL, 0xf, 0xf, true);
    return v + __int_as_float(t);
}
__device__ __forceinline__ float row16_sum(float v) {
    v = dpp_add<0xB1>(v);   // quad_perm xor1
    v = dpp_add<0x4E>(v);   // quad_perm xor2
    v = dpp_add<0x124>(v);  // row_ror:4
    v = dpp_add<0x128>(v);  // row_ror:8
    return v;
}

// XOR bank swizzle (keeps phase-1 scatter at free 2-way aliasing)
__device__ __forceinline__ int sw(int b) { return ((b ^ (b >> 2)) & 3) << 3; }

// Block: 512 threads = 8 waves; one (r, 16-batch slice). 32 KB LDS -> 4 blocks/CU
// = 32 waves/CU (100% occupancy cap) during phase 1.
// Phase 1: u_hat[16b x 512n] via 3-term 2-way-RNE-split bf16 MFMA
//   (a2*b1 + a1*b2 + a1*b1, smallest first) -> rel err ~2^-16.5.
//   Wave w covers n-tiles 4w..4w+3.
// Phase 2: first 4 waves; thread=(b=tid>>4, j=tid&15) owns o={2j,2j+1};
//   routing in registers, reductions via DPP row16_sum.
__global__ __launch_bounds__(512, 8)
void capsule_routing_kernel(const float* __restrict__ x,
                            const float* __restrict__ W,
                            float* __restrict__ out) {
    __shared__ float u_lds[BB * 512];   // 32 KB

    const int tid = threadIdx.x;
    const int bid = blockIdx.x;
    const int r   = bid >> 2;
    const int b0  = (bid & 3) * BB;

    // ---------------- Phase 1: split-bf16 MFMA u_hat ----------------
    {
        const int lane = tid & 63;
        const int w    = tid >> 6;     // wave 0..7 -> n-tiles 4w..4w+3
        const int q    = lane >> 4;    // k-quad (2,3 = zero pad)
        const int np   = lane & 15;    // m (batch) for A / n-col for B

        const short8 z8 = {0,0,0,0,0,0,0,0};
        Split2 as; as.h1 = z8; as.h2 = z8;
        if (q < 2)
            as = split2x8(x + ((size_t)(b0 + np) * R_DIM + r) * I_DIM + q * 8);

        const f32x4 zero4 = {0.f, 0.f, 0.f, 0.f};
        f32x4 acc[4];
        #pragma unroll
        for (int t = 0; t < 4; ++t) {
            const int ntile = w * 4 + t;
            Split2 bs; bs.h1 = z8; bs.h2 = z8;
            if (q < 2)
                bs = split2x8(W + ((size_t)r * 512 + ntile * 16 + np) * I_DIM + q * 8);

            // smallest terms first: a2*b1, a1*b2 (~2^-9), then a1*b1
            f32x4 a = __builtin_amdgcn_mfma_f32_16x16x32_bf16(as.h2, bs.h1, zero4, 0, 0, 0);
            a = __builtin_amdgcn_mfma_f32_16x16x32_bf16(as.h1, bs.h2, a, 0, 0, 0);
            a = __builtin_amdgcn_mfma_f32_16x16x32_bf16(as.h1, bs.h1, a, 0, 0, 0);
            acc[t] = a;
        }

        // C/D: col = lane&15 (n within tile), row = q*4+reg (batch)
        #pragma unroll
        for (int t = 0; t < 4; ++t) {
            const int col = (w * 4 + t) * 16 + np;
            #pragma unroll
            for (int reg = 0; reg < 4; ++reg) {
                const int row = q * 4 + reg;
                u_lds[row * 512 + (col ^ sw(row))] = acc[t][reg];
            }
        }
    }
    __syncthreads();

    // ---------------- Phase 2: dynamic routing (first 4 waves) ----------------
    if (tid < 256) {
        const int b = tid >> 4;    // 0..15 local batch
        const int j = tid & 15;    // o-pair index
        const int s = sw(b);

        float u2[32];              // u_hat[b][c][o=2j,2j+1]
        #pragma unroll
        for (int c = 0; c < 16; ++c) {
            const float2 v2 = *(const float2*)&u_lds[b * 512 + ((c * 32 + 2 * j) ^ s)];
            u2[2 * c]     = v2.x;
            u2[2 * c + 1] = v2.y;
        }

        float bv[16];
        #pragma unroll
        for (int c = 0; c < 16; ++c) bv[c] = 0.0f;

        float s0 = 0.f, s1 = 0.f, g = 0.f;

        #pragma unroll
        for (int it = 0; it < 3; ++it) {
            if (it == 0) {
                s0 = 0.f; s1 = 0.f;
                #pragma unroll
                for (int c = 0; c < 16; ++c) { s0 += u2[2*c]; s1 += u2[2*c+1]; }
                s0 *= 0.0625f; s1 *= 0.0625f;
            } else {
                float m = bv[0];
                #pragma unroll
                for (int c = 1; c < 16; ++c) m = fmaxf(m, bv[c]);
                float Z = 0.f; s0 = 0.f; s1 = 0.f;
                #pragma unroll
                for (int c = 0; c < 16; ++c) {
                    const float e = __expf(bv[c] - m);
                    Z += e;
                    s0 = fmaf(e, u2[2*c],   s0);
                    s1 = fmaf(e, u2[2*c+1], s1);
                }
                const float rZ = __builtin_amdgcn_rcpf(Z);
                s0 *= rZ; s1 *= rZ;
            }

            // g = ||s|| / (1 + ||s||^2), norm over 32 o's (16 lanes x 2)
            const float nn = row16_sum(s0 * s0 + s1 * s1);
            g = sqrtf(nn) * __builtin_amdgcn_rcpf(1.0f + nn);

            if (it < 2) {
                #pragma unroll
                for (int c = 0; c < 16; ++c) {
                    const float t = row16_sum(fmaf(u2[2*c], s0, u2[2*c+1] * s1));
                    bv[c] = fmaf(g, t, bv[c]);
                }
            }
        }

        const float2 o2 = make_float2(g * s0, g * s1);
        *(float2*)(out + ((size_t)(b0 + b) * R_DIM + r) * O_DIM + 2 * j) = o2;
    }
}

extern "C" void kernel_launch(void* const* d_in, const int* in_sizes, int n_in,
                              void* d_out, int out_size, void* d_ws, size_t ws_size,
                              hipStream_t stream) {
    const float* x   = (const float*)d_in[0];   // [64, 2048, 16]
    const float* W   = (const float*)d_in[1];   // [2048, 16, 32, 16]
    float*       out = (float*)d_out;           // [64, 2048, 32]

    dim3 grid(R_DIM * (B_DIM / BB));            // 8192 blocks
    dim3 block(512);
    hipLaunchKernelGGL(capsule_routing_kernel, grid, block, 0, stream, x, W, out);
}

// Round 6
// 143.587 us; speedup vs baseline: 1.4949x; 1.0812x over previous
//
#include <hip/hip_runtime.h>

#define R_DIM 2048
#define O_DIM 32
#define I_DIM 16
#define B_DIM 64
#define BB 16   // batch rows per block

typedef _Float16 half8  __attribute__((ext_vector_type(8)));
typedef float    f32x4  __attribute__((ext_vector_type(4)));

struct SplitH { half8 h1, h2; };

// 2-way fp16 split of 8 consecutive fp32 via HW packed-cvt (RTZ):
// x = h1 + h2 + O(2^-22 * x). ~3 VALU/elem vs 11 for manual bf16.
__device__ __forceinline__ SplitH splitf16x8(const float* __restrict__ p) {
    float f[8];
    *(float4*)(f)     = *(const float4*)(p);
    *(float4*)(f + 4) = *(const float4*)(p + 4);
    SplitH r;
    #pragma unroll
    for (int j = 0; j < 4; ++j) {
        const auto a = __builtin_amdgcn_cvt_pkrtz(f[2*j], f[2*j+1]);   // __fp16 x2
        const float r0 = f[2*j]     - (float)a[0];
        const float r1 = f[2*j + 1] - (float)a[1];
        const auto c = __builtin_amdgcn_cvt_pkrtz(r0, r1);
        r.h1[2*j] = (_Float16)a[0]; r.h1[2*j+1] = (_Float16)a[1];
        r.h2[2*j] = (_Float16)c[0]; r.h2[2*j+1] = (_Float16)c[1];
    }
    return r;
}

// DPP 16-lane (row) all-reduce — pure VALU pipe.
template<int CTRL>
__device__ __forceinline__ float dpp_mv(float v) {
    int t = __builtin_amdgcn_update_dpp(0, __float_as_int(v), CTRL, 0xf, 0xf, true);
    return __int_as_float(t);
}
__device__ __forceinline__ float row16_sum(float v) {
    v += dpp_mv<0xB1>(v);    // quad_perm xor1
    v += dpp_mv<0x4E>(v);    // quad_perm xor2
    v += dpp_mv<0x124>(v);   // row_ror:4
    v += dpp_mv<0x128>(v);   // row_ror:8
    return v;
}
__device__ __forceinline__ float row16_max(float v) {
    v = fmaxf(v, dpp_mv<0xB1>(v));
    v = fmaxf(v, dpp_mv<0x4E>(v));
    v = fmaxf(v, dpp_mv<0x124>(v));
    v = fmaxf(v, dpp_mv<0x128>(v));
    return v;
}

// LDS swizzle for u_hat[b][col], col = c*32+o:
//  - sw(b) (2 bits into bank bits 3-4): phase-1 C-scatter conflict-free
//  - (c&7)<<2 (bank bits 2-4): o-major b128 reads bank-uniform
__device__ __forceinline__ int swaddr(int b, int col) {
    return b * 512 + (col ^ (((b ^ (b >> 2)) & 3) << 3) ^ (((col >> 5) & 7) << 2));
}

// Block: 512 threads = 8 waves; one (r, 16-batch slice); 4 blocks/CU.
// Phase 1 (all waves): u_hat[16b x 512n] via 3-term fp16-split MFMA
//   (a2*b1 + a1*b2 + a1*b1), rel err ~2^-22. Wave w covers n-tiles 4w..4w+3.
// Phase 2 wave-specialized:
//   waves 0-3 ("A"): thread=(b, j) o-pair; computes s, squash, v; writes v_lds.
//   waves 4-7 ("B"): thread=(b, c); holds u_hat o-major; softmax (1 exp/thread)
//   + agreement as 32 FMAs vs broadcast v_lds reads (no DPP reductions).
__global__ __launch_bounds__(512, 8)
void capsule_routing_kernel(const float* __restrict__ x,
                            const float* __restrict__ W,
                            float* __restrict__ out) {
    __shared__ float u_lds[BB * 512];   // 32 KB, swizzled
    __shared__ float w_lds[BB * 16];    // softmax weights
    __shared__ float v_lds[BB * 36];    // v vectors (stride 36: bank spread)

    const int tid = threadIdx.x;
    const int bid = blockIdx.x;
    const int r   = bid >> 2;
    const int b0  = (bid & 3) * BB;

    // ---------------- Phase 1: fp16-split MFMA u_hat ----------------
    {
        const int lane = tid & 63;
        const int w    = tid >> 6;     // wave 0..7 -> n-tiles 4w..4w+3
        const int q    = lane >> 4;    // k-quad (2,3 = zero pad)
        const int np   = lane & 15;    // m (batch) for A / n-col for B

        const half8 z8 = {0,0,0,0,0,0,0,0};
        SplitH as; as.h1 = z8; as.h2 = z8;
        if (q < 2)
            as = splitf16x8(x + ((size_t)(b0 + np) * R_DIM + r) * I_DIM + q * 8);

        const f32x4 zero4 = {0.f, 0.f, 0.f, 0.f};
        f32x4 acc[4];
        #pragma unroll
        for (int t = 0; t < 4; ++t) {
            SplitH bs; bs.h1 = z8; bs.h2 = z8;
            if (q < 2)
                bs = splitf16x8(W + ((size_t)r * 512 + (w * 4 + t) * 16 + np) * I_DIM + q * 8);

            f32x4 a = __builtin_amdgcn_mfma_f32_16x16x32_f16(as.h2, bs.h1, zero4, 0, 0, 0);
            a = __builtin_amdgcn_mfma_f32_16x16x32_f16(as.h1, bs.h2, a, 0, 0, 0);
            a = __builtin_amdgcn_mfma_f32_16x16x32_f16(as.h1, bs.h1, a, 0, 0, 0);
            acc[t] = a;
        }

        #pragma unroll
        for (int t = 0; t < 4; ++t) {
            const int col = (w * 4 + t) * 16 + np;
            #pragma unroll
            for (int reg = 0; reg < 4; ++reg)
                u_lds[swaddr(q * 4 + reg, col)] = acc[t][reg];
        }
    }
    __syncthreads();

    // ---------------- Phase 2: wave-specialized routing ----------------
    const bool isA = (tid < 256);
    const int  b   = (tid >> 4) & 15;
    const int  jc  = tid & 15;          // j (A) / c (B)

    float ureg[32];                     // A: c-major o-pairs; B: o-major (shared regs)
    float bv = 0.0f;                    // B only
    if (isA) {
        #pragma unroll
        for (int c = 0; c < 16; ++c) {
            const float2 v2 = *(const float2*)&u_lds[swaddr(b, c * 32 + 2 * jc)];
            ureg[2 * c] = v2.x; ureg[2 * c + 1] = v2.y;
        }
    } else {
        #pragma unroll
        for (int oc = 0; oc < 8; ++oc) {
            const float4 v4 = *(const float4*)&u_lds[swaddr(b, jc * 32 + 4 * oc)];
            ureg[4*oc+0] = v4.x; ureg[4*oc+1] = v4.y;
            ureg[4*oc+2] = v4.z; ureg[4*oc+3] = v4.w;
        }
    }

    float s0 = 0.f, s1 = 0.f, g = 0.f;

    #pragma unroll
    for (int it = 0; it < 3; ++it) {
        if (it > 0) {
            if (!isA) {
                const float m = row16_max(bv);
                const float e = __expf(bv - m);
                const float Z = row16_sum(e);
                w_lds[b * 16 + jc] = e * __builtin_amdgcn_rcpf(Z);
            }
            __syncthreads();
        }
        if (isA) {
            if (it == 0) {
                s0 = 0.f; s1 = 0.f;
                #pragma unroll
                for (int c = 0; c < 16; ++c) { s0 += ureg[2*c]; s1 += ureg[2*c+1]; }
                s0 *= 0.0625f; s1 *= 0.0625f;
            } else {
                s0 = 0.f; s1 = 0.f;
                #pragma unroll
                for (int c4 = 0; c4 < 4; ++c4) {
                    const float4 wc = *(const float4*)&w_lds[b * 16 + 4 * c4];
                    s0 = fmaf(wc.x, ureg[8*c4+0], s0); s1 = fmaf(wc.x, ureg[8*c4+1], s1);
                    s0 = fmaf(wc.y, ureg[8*c4+2], s0); s1 = fmaf(wc.y, ureg[8*c4+3], s1);
                    s0 = fmaf(wc.z, ureg[8*c4+4], s0); s1 = fmaf(wc.z, ureg[8*c4+5], s1);
                    s0 = fmaf(wc.w, ureg[8*c4+6], s0); s1 = fmaf(wc.w, ureg[8*c4+7], s1);
                }
            }
            const float nn = row16_sum(s0 * s0 + s1 * s1);   // over j-lanes
            g = sqrtf(nn) * __builtin_amdgcn_rcpf(1.0f + nn);
            if (it < 2) {
                *(float2*)&v_lds[b * 36 + 2 * jc] = make_float2(g * s0, g * s1);
            } else {
                *(float2*)(out + ((size_t)(b0 + b) * R_DIM + r) * O_DIM + 2 * jc)
                    = make_float2(g * s0, g * s1);
            }
        }
        if (it < 2) {
            __syncthreads();
            if (!isA) {
                float t = 0.f;
                #pragma unroll
                for (int oc = 0; oc < 8; ++oc) {      // broadcast reads (free)
                    const float4 vv = *(const float4*)&v_lds[b * 36 + 4 * oc];
                    t = fmaf(ureg[4*oc+0], vv.x, t);
                    t = fmaf(ureg[4*oc+1], vv.y, t);
                    t = fmaf(ureg[4*oc+2], vv.z, t);
                    t = fmaf(ureg[4*oc+3], vv.w, t);
                }
                bv += t;
            }
        }
    }
}

extern "C" void kernel_launch(void* const* d_in, const int* in_sizes, int n_in,
                              void* d_out, int out_size, void* d_ws, size_t ws_size,
                              hipStream_t stream) {
    const float* x   = (const float*)d_in[0];   // [64, 2048, 16]
    const float* W   = (const float*)d_in[1];   // [2048, 16, 32, 16]
    float*       out = (float*)d_out;           // [64, 2048, 32]

    dim3 grid(R_DIM * (B_DIM / BB));            // 8192 blocks
    dim3 block(512);
    hipLaunchKernelGGL(capsule_routing_kernel, grid, block, 0, stream, x, W, out);
}